// Round 9
// baseline (60.694 us; speedup 1.0000x reference)
//
#include <hip/hip_runtime.h>

// out[n,m] = -sum_d |x[n,d]-y[m,d]|  N=M=2048, D=128, fp32.  VALU-bound.
// R7 proved: asm-pin keeps y resident (VGPR=48, FETCH 4.6MB clean); grid
// capped occupancy at 4 waves/SIMD. R4 proved: SMEM x-path is the fastest
// structure (32.6us even WITH y-remat). R8 = R4 structure + R7 pin +
// ROWS=8 -> 8192 waves = 2048 blocks = 8 blocks/CU = 8 waves/SIMD
// (live set ~52 VGPR <= 64 budget, fits naturally -- no min-waves bound,
// that was R6's spill disaster).
//  - x rows wave-uniform -> constant-AS s_load (SMEM pipe, data in SGPRs,
//    v_sub_f32 v,s,v). readfirstlane makes wave id provably uniform.
//  - y chunk (32 floats = 8 f4 = 32 VGPR) per-lane, asm-pinned.
// Floor ~17us at 8 waves/SIMD; predict 22-27.

typedef float f4 __attribute__((ext_vector_type(4)));
typedef __attribute__((address_space(4))) const f4 cf4;

#define DD 128
#define ROWS 8    // rows per wave
#define NCH 4     // d-chunks of 32 floats

__launch_bounds__(256)
__global__ void l1_dist_kernel(const float* __restrict__ X,
                               const float* __restrict__ Y,
                               float* __restrict__ out,
                               int N, int M) {
    const int wave = __builtin_amdgcn_readfirstlane((int)(threadIdx.x >> 6));
    const int lane = threadIdx.x & 63;
    const int gw = blockIdx.x * 4 + wave;   // 0..8191
    const int mg = gw & 31;                 // 32 column groups (64 cols)
    const int rg = gw >> 5;                 // 256 row groups (8 rows)
    const int m  = mg * 64 + lane;
    const int n0 = rg * ROWS;

    float acc[ROWS];
#pragma unroll
    for (int r = 0; r < ROWS; ++r) acc[r] = 0.f;

#pragma unroll 1   // chunks strictly sequential: live set stays ~52 VGPR
    for (int c = 0; c < NCH; ++c) {
        // This lane's y chunk: 8 f4 = 32 VGPR, pinned non-rematerializable.
        f4 yv[8];
        const f4* yp = (const f4*)(Y + (size_t)m * DD + c * 32);
#pragma unroll
        for (int k = 0; k < 8; ++k) {
            yv[k] = yp[k];
            asm volatile("" : "+v"(yv[k]));
        }

#pragma unroll
        for (int r = 0; r < ROWS; ++r) {
            // wave-uniform, constant AS -> 2x s_load_dwordx16 on SMEM pipe
            cf4* xp = (cf4*)(X + (size_t)(n0 + r) * DD + c * 32);
            float a0 = 0.f, a1 = 0.f, a2 = 0.f, a3 = 0.f;
#pragma unroll
            for (int k = 0; k < 8; ++k) {
                f4 xv = xp[k];
                a0 += __builtin_fabsf(xv.x - yv[k].x);
                a1 += __builtin_fabsf(xv.y - yv[k].y);
                a2 += __builtin_fabsf(xv.z - yv[k].z);
                a3 += __builtin_fabsf(xv.w - yv[k].w);
            }
            acc[r] += (a0 + a1) + (a2 + a3);
        }
    }

#pragma unroll
    for (int r = 0; r < ROWS; ++r)
        out[(size_t)(n0 + r) * M + m] = -acc[r];   // 256B coalesced/wave

}

extern "C" void kernel_launch(void* const* d_in, const int* in_sizes, int n_in,
                              void* d_out, int out_size, void* d_ws, size_t ws_size,
                              hipStream_t stream) {
    const float* x = (const float*)d_in[0];
    const float* y = (const float*)d_in[1];
    float* out = (float*)d_out;
    const int N = in_sizes[0] / DD;   // 2048
    const int M = in_sizes[1] / DD;   // 2048
    const int waves = (M / 64) * (N / ROWS);  // 8192
    dim3 grid(waves / 4);                     // 2048 blocks of 256 threads
    l1_dist_kernel<<<grid, 256, 0, stream>>>(x, y, out, N, M);
}

// Round 10
// 47.722 us; speedup vs baseline: 1.2718x; 1.2718x over previous
//
#include <hip/hip_runtime.h>

// out[n,m] = -sum_d |x[n,d]-y[m,d]|  N=M=2048, D=128, fp32.  VALU-bound.
// R8 post-mortem: per-lane y gather = 64 distinct cache lines per load
// instr (512B lane stride) -> TA/L1-bound, cost ~= all VALU work.
// R9: all global traffic coalesced.
//  - y tile (64 cols x 128 floats = 32KB) staged to LDS ONCE, coalesced,
//    f4-XOR swizzle (R3-validated: 0 conflicts). Per chunk each lane pulls
//    its column's 8xf4 into regs (asm-pinned, R7-validated: no remat).
//  - x rows via constant-AS s_load on SMEM pipe (R2/R4-validated; zero
//    VGPR, zero DS). readfirstlane makes wave id provably uniform.
//  - block = 64 rows x 64 cols, 4 waves x 16 rows; grid 32x32=1024
//    = 4 blocks/CU (LDS 128KB/CU); (256,2) -- the only no-spill bound.
// VALU floor 13.7us; DS/CU ~6k cyc << 33k; predict 18-24us.

typedef float f4 __attribute__((ext_vector_type(4)));
typedef __attribute__((address_space(4))) const f4 cf4;

#define DD 128
#define BROWS 64
#define BCOLS 64
#define ROWS 16   // rows per wave
#define NCH 4     // d-chunks of 32 floats (8 f4)

__launch_bounds__(256, 2)
__global__ void l1_dist_kernel(const float* __restrict__ X,
                               const float* __restrict__ Y,
                               float* __restrict__ out,
                               int N, int M) {
    __shared__ f4 ys[BCOLS * 32];   // 64 y-rows x 32 f4 = 32 KB, swizzled

    const int tid  = threadIdx.x;
    const int wave = __builtin_amdgcn_readfirstlane((int)(threadIdx.x >> 6));
    const int lane = tid & 63;
    const int brow = blockIdx.y * BROWS;
    const int bcol = blockIdx.x * BCOLS;
    const int n0   = brow + wave * ROWS;   // this wave's row base
    const int m    = bcol + lane;          // this lane's column (y row)

    // Stage y tile coalesced: 64 rows x 32 f4 = 2048 f4; 256 thr -> 8 each.
    // Swizzle: phys slot = q ^ (r & 31)  (bitwise, bijective per row).
#pragma unroll
    for (int k = 0; k < 8; ++k) {
        int idx = tid + k * 256;
        int r = idx >> 5, q = idx & 31;
        ys[r * 32 + (q ^ (r & 31))] =
            *(const f4*)&Y[(size_t)(bcol + r) * DD + (q << 2)];
    }
    __syncthreads();

    float acc[ROWS];
#pragma unroll
    for (int r = 0; r < ROWS; ++r) acc[r] = 0.f;

#pragma unroll 1   // chunks strictly sequential: live set stays ~60 VGPR
    for (int c = 0; c < NCH; ++c) {
        // Lane's y chunk from LDS (swizzled, conflict-free), pinned in regs.
        f4 yv[8];
#pragma unroll
        for (int k = 0; k < 8; ++k) {
            yv[k] = ys[lane * 32 + ((c * 8 + k) ^ (lane & 31))];
            asm volatile("" : "+v"(yv[k]));
        }

#pragma unroll 2   // 2 rows in flight: s_loads of r+1 issue under r compute
        for (int r = 0; r < ROWS; ++r) {
            cf4* xp = (cf4*)(X + (size_t)(n0 + r) * DD + c * 32);  // uniform
            float a0 = 0.f, a1 = 0.f, a2 = 0.f, a3 = 0.f;
#pragma unroll
            for (int k = 0; k < 8; ++k) {
                f4 xv = xp[k];   // s_load_dwordx16 pair on SMEM pipe
                a0 += __builtin_fabsf(xv.x - yv[k].x);
                a1 += __builtin_fabsf(xv.y - yv[k].y);
                a2 += __builtin_fabsf(xv.z - yv[k].z);
                a3 += __builtin_fabsf(xv.w - yv[k].w);
            }
            acc[r] += (a0 + a1) + (a2 + a3);
        }
    }

#pragma unroll
    for (int r = 0; r < ROWS; ++r)
        out[(size_t)(n0 + r) * M + m] = -acc[r];   // 256B coalesced/wave
}

extern "C" void kernel_launch(void* const* d_in, const int* in_sizes, int n_in,
                              void* d_out, int out_size, void* d_ws, size_t ws_size,
                              hipStream_t stream) {
    const float* x = (const float*)d_in[0];
    const float* y = (const float*)d_in[1];
    float* out = (float*)d_out;
    const int N = in_sizes[0] / DD;   // 2048
    const int M = in_sizes[1] / DD;   // 2048
    dim3 grid(M / BCOLS, N / BROWS);  // (32, 32) = 1024 blocks
    l1_dist_kernel<<<grid, 256, 0, stream>>>(x, y, out, N, M);
}

// Round 11
// 46.723 us; speedup vs baseline: 1.2990x; 1.0214x over previous
//
#include <hip/hip_runtime.h>

// out[n,m] = -sum_d |x[n,d]-y[m,d]|  N=M=2048, D=128, fp32.  VALU-bound.
// Evidence R2-R9: LDS hops cost ~15us each way; fastest remains R4
// (SMEM-x + per-lane-global-y, ROWS=16, 32.6us) whose only dirty counter
// was FETCH doubling (y remat). R10 = EXACT R4 + asm pins on yv (pins
// proven to hold residency in R7/R9). Minimal diff vs R4 (pins only) and
// vs R8 (ROWS only) -- isolates the remat cost.
//  - x rows wave-uniform -> constant-AS s_load (SMEM pipe, data in SGPRs,
//    v_sub_f32 v,s,v consumes directly; zero VGPR cost).
//  - y chunk: 32 floats = 8 f4 = 32 VGPR per lane, pinned.
//  - 4096 waves = 1024 blocks = 4 blocks/CU; live ~56 VGPR fits the
//    default 64-VGPR/8-wave allocator target (no min-waves coercion).

typedef float f4 __attribute__((ext_vector_type(4)));
typedef __attribute__((address_space(4))) const f4 cf4;

#define DD 128
#define ROWS 16   // rows per wave
#define NCH 4     // d-chunks of 32 floats

__launch_bounds__(256)
__global__ void l1_dist_kernel(const float* __restrict__ X,
                               const float* __restrict__ Y,
                               float* __restrict__ out,
                               int N, int M) {
    const int wave = __builtin_amdgcn_readfirstlane((int)(threadIdx.x >> 6));
    const int lane = threadIdx.x & 63;
    const int gw = blockIdx.x * 4 + wave;   // 0..4095
    const int mg = gw & 31;                 // 32 column groups (64 cols)
    const int rg = gw >> 5;                 // 128 row groups (16 rows)
    const int m  = mg * 64 + lane;
    const int n0 = rg * ROWS;

    float acc[ROWS];
#pragma unroll
    for (int r = 0; r < ROWS; ++r) acc[r] = 0.f;

#pragma unroll 1   // chunks strictly sequential: live set stays ~56 VGPR
    for (int c = 0; c < NCH; ++c) {
        // This lane's y chunk: 8 f4 = 32 VGPR, pinned non-rematerializable.
        f4 yv[8];
        const f4* yp = (const f4*)(Y + (size_t)m * DD + c * 32);
#pragma unroll
        for (int k = 0; k < 8; ++k) {
            yv[k] = yp[k];
            asm volatile("" : "+v"(yv[k]));
        }

#pragma unroll
        for (int r = 0; r < ROWS; ++r) {
            // wave-uniform, constant AS -> 2x s_load_dwordx16 on SMEM pipe
            cf4* xp = (cf4*)(X + (size_t)(n0 + r) * DD + c * 32);
            float a0 = 0.f, a1 = 0.f, a2 = 0.f, a3 = 0.f;
#pragma unroll
            for (int k = 0; k < 8; ++k) {
                f4 xv = xp[k];
                a0 += __builtin_fabsf(xv.x - yv[k].x);
                a1 += __builtin_fabsf(xv.y - yv[k].y);
                a2 += __builtin_fabsf(xv.z - yv[k].z);
                a3 += __builtin_fabsf(xv.w - yv[k].w);
            }
            acc[r] += (a0 + a1) + (a2 + a3);
        }
    }

#pragma unroll
    for (int r = 0; r < ROWS; ++r)
        out[(size_t)(n0 + r) * M + m] = -acc[r];   // 256B coalesced/wave
}

extern "C" void kernel_launch(void* const* d_in, const int* in_sizes, int n_in,
                              void* d_out, int out_size, void* d_ws, size_t ws_size,
                              hipStream_t stream) {
    const float* x = (const float*)d_in[0];
    const float* y = (const float*)d_in[1];
    float* out = (float*)d_out;
    const int N = in_sizes[0] / DD;   // 2048
    const int M = in_sizes[1] / DD;   // 2048
    const int waves = (M / 64) * (N / ROWS);  // 4096
    dim3 grid(waves / 4);                     // 1024 blocks of 256 threads
    l1_dist_kernel<<<grid, 256, 0, stream>>>(x, y, out, N, M);
}

// Round 13
// 44.085 us; speedup vs baseline: 1.3767x; 1.0598x over previous
//
#include <hip/hip_runtime.h>

// out[n,m] = -sum_d |x[n,d]-y[m,d]|  N=M=2048, D=128, fp32 in/out.
// R11 failed (absmax 95 = structural corruption in exotic constructs:
// cvt_pkrtz/u4 pack, XOR swizzle, fdot2 -- could not isolate). R12 keeps
// the f16 idea (2x LDS density; DS pipe was the proven binding pipe) with
// ONLY plain constructs:
//  - padded LDS rows (LDH=136 halves = 272B): y-reads 2-way (free),
//    x-reads broadcast 2-way, staged writes at the 8-cyc data floor.
//  - scalar (_Float16) RNE casts fused into staging (no pkrtz packing).
//  - compute: h8 vector sub + elementwise_abs + f16 fold 8->4->2 (<=8-term
//    partials, err ~0.1) + f32 flush per dq. 15 VALU / 8 elems.
// Tile 64x128, whole D staged once (52KB, ONE barrier), 512 blocks = 2/CU.
// VALU floor ~13us; DS 12.3k cyc/CU vs 30.7k VALU window (40%).

typedef float f4 __attribute__((ext_vector_type(4)));
typedef _Float16 h8 __attribute__((ext_vector_type(8)));
typedef _Float16 h4 __attribute__((ext_vector_type(4)));
typedef _Float16 h2 __attribute__((ext_vector_type(2)));

#define DD 128
#define XR 64     // x rows per block
#define YC 128    // y cols per block
#define LDH 136   // LDS row stride in halves (128 + 8 pad)
#define TM 4
#define TN 8

__launch_bounds__(256, 2)
__global__ void l1_dist_kernel(const float* __restrict__ X,
                               const float* __restrict__ Y,
                               float* __restrict__ out,
                               int N, int M) {
    __shared__ _Float16 sh[(XR + YC) * LDH];   // 52224 B
    _Float16* xsh = sh;
    _Float16* ysh = sh + XR * LDH;

    const int tid  = threadIdx.x;
    const int brow = blockIdx.y * XR;
    const int bcol = blockIdx.x * YC;

    // ---- Stage + convert (RNE casts). Granule = 8 halves; 16 per row.
#pragma unroll
    for (int k = 0; k < 4; ++k) {              // x: 64 rows x 16 granules
        int idx = tid + k * 256;
        int r = idx >> 4, g = idx & 15;
        const float* s = &X[(size_t)(brow + r) * DD + g * 8];
        f4 a = *(const f4*)s, b = *(const f4*)(s + 4);
        _Float16* dst = &xsh[r * LDH + g * 8];
        dst[0] = (_Float16)a.x; dst[1] = (_Float16)a.y;
        dst[2] = (_Float16)a.z; dst[3] = (_Float16)a.w;
        dst[4] = (_Float16)b.x; dst[5] = (_Float16)b.y;
        dst[6] = (_Float16)b.z; dst[7] = (_Float16)b.w;
    }
#pragma unroll
    for (int k = 0; k < 8; ++k) {              // y: 128 rows x 16 granules
        int idx = tid + k * 256;
        int r = idx >> 4, g = idx & 15;
        const float* s = &Y[(size_t)(bcol + r) * DD + g * 8];
        f4 a = *(const f4*)s, b = *(const f4*)(s + 4);
        _Float16* dst = &ysh[r * LDH + g * 8];
        dst[0] = (_Float16)a.x; dst[1] = (_Float16)a.y;
        dst[2] = (_Float16)a.z; dst[3] = (_Float16)a.w;
        dst[4] = (_Float16)b.x; dst[5] = (_Float16)b.y;
        dst[6] = (_Float16)b.z; dst[7] = (_Float16)b.w;
    }
    __syncthreads();

    const int tc = tid & 15;    // col group: cols tc + 16*j
    const int tr = tid >> 4;    // row group: rows tr*4 + i

    float acc[TM][TN];
#pragma unroll
    for (int i = 0; i < TM; ++i)
#pragma unroll
        for (int j = 0; j < TN; ++j) acc[i][j] = 0.f;

#pragma unroll 1
    for (int dq = 0; dq < 16; ++dq) {          // 8 d's per iteration
        h8 xv[TM], yv[TN];
#pragma unroll
        for (int i = 0; i < TM; ++i)
            xv[i] = *(const h8*)&xsh[(tr * 4 + i) * LDH + dq * 8];
#pragma unroll
        for (int j = 0; j < TN; ++j)
            yv[j] = *(const h8*)&ysh[(tc + 16 * j) * LDH + dq * 8];

#pragma unroll
        for (int i = 0; i < TM; ++i)
#pragma unroll
            for (int j = 0; j < TN; ++j) {
                h8 d  = xv[i] - yv[j];                 // 4x v_pk_add_f16
                h8 ad = __builtin_elementwise_abs(d);  // sign-mask ANDs
                h4 lo = __builtin_shufflevector(ad, ad, 0, 1, 2, 3);
                h4 hi = __builtin_shufflevector(ad, ad, 4, 5, 6, 7);
                h4 s4 = lo + hi;                       // 2x v_pk_add_f16
                h2 s2 = __builtin_shufflevector(s4, s4, 0, 1)
                      + __builtin_shufflevector(s4, s4, 2, 3);  // 1x pk
                acc[i][j] += (float)s2[0] + (float)s2[1];       // f32 flush
            }
    }

#pragma unroll
    for (int i = 0; i < TM; ++i) {
        int r = brow + tr * 4 + i;
#pragma unroll
        for (int j = 0; j < TN; ++j) {
            int cl = bcol + tc + 16 * j;
            out[(size_t)r * M + cl] = -acc[i][j];
        }
    }
}

extern "C" void kernel_launch(void* const* d_in, const int* in_sizes, int n_in,
                              void* d_out, int out_size, void* d_ws, size_t ws_size,
                              hipStream_t stream) {
    const float* x = (const float*)d_in[0];
    const float* y = (const float*)d_in[1];
    float* out = (float*)d_out;
    const int N = in_sizes[0] / DD;   // 2048
    const int M = in_sizes[1] / DD;   // 2048
    dim3 grid(M / YC, N / XR);        // (16, 32) = 512 blocks
    l1_dist_kernel<<<grid, 256, 0, stream>>>(x, y, out, N, M);
}